// Round 12
// baseline (113.099 us; speedup 1.0000x reference)
//
#include <hip/hip_runtime.h>
#include <hip/hip_bf16.h>
#include <math.h>

#define C 8
#define K 128
#define S 64
#define L 2048
#define NB 64
#define W (L - S + 1)   // 1985
#define TW 256          // windows per tile
#define NT 8            // tiles per block (8*256 = 2048 >= 1985)
#define XCS 336         // xcop stride shorts: 168 dw == 8 mod 32 -> <=2-way on A b64 reads
#define XFS 344         // xf stride floats (336 data + 8 zero pad)

typedef __attribute__((ext_vector_type(8))) short bf16x8;
typedef __attribute__((ext_vector_type(4))) short short4v;
typedef __attribute__((ext_vector_type(4))) float f32x4;

// packed f32x2 -> bf16x2 (v_cvt_pk_bf16_f32 on gfx950); .x -> low short
__device__ __forceinline__ unsigned int pkbf(float a, float b) {
  __hip_bfloat162 h = __float22bfloat162_rn(make_float2(a, b));
  return *reinterpret_cast<unsigned int*>(&h);
}

// ONE kernel. Block owns (n, kblk: 32 k). Z-norm done in-block into resident
// LDS B (no prep kernel, no global round-trip). 8 w-tiles x 256 w; channel
// loop barrier-free; plain store at end (no atomics, no out-init).
__global__ __launch_bounds__(512, 4) void mega_kernel(const float* __restrict__ x,
                                                      const float* __restrict__ sh,
                                                      float* __restrict__ out) {
  __shared__ __align__(16) unsigned short blds[C * 4 * 512];   // 32 KB [c][kt2][ks2][512]
  __shared__ __align__(16) unsigned short xcop[C][4][XCS];     // 21 KB shifted bf16 copies
  __shared__ __align__(16) float xf[C * XFS];                  // 10.75 KB fp32 x staging
  __shared__ __align__(16) float sqx[C][TW];                   // 8 KB (includes +64 bias)

  const int t = threadIdx.x;
  const int lane = t & 63;
  const int wave = t >> 6;     // 0..7
  const int wgrp = wave >> 1;  // 0..3 : w-offset 64*wgrp within tile
  const int kgrp = wave & 1;   // 0..1 : k-offset 16*kgrp
  const int col = lane & 15;
  const int quad = lane >> 4;
  const int r4 = col & 3;
  const int kblk = blockIdx.x; // 0..3
  const int n = blockIdx.y;
  const float* xn = x + (size_t)n * C * L;

  // ---- stage xf for tile 0 ----
  {
    const int w0 = 0;
#pragma unroll
    for (int j = 0; j < 6; ++j) {
      int s = j * 512 + t;
      if (s < C * XFS) {
        int c = s / XFS, e = s - c * XFS;
        int g = w0 + e;
        xf[s] = (e < 336 && g < L) ? xn[c * L + g] : 0.0f;
      }
    }
  }
  // ---- in-block z-norm of this kblk's 32 shapelets (threads 0..255) ----
  if (t < 256) {
    int c = t >> 5, kl = t & 31;
    const float4* sp = (const float4*)(sh + ((size_t)c * K + kblk * 32 + kl) * S);
    float4 v[16];
#pragma unroll
    for (int j = 0; j < 16; ++j) v[j] = sp[j];
    float s1 = 0.f, s2 = 0.f;
#pragma unroll
    for (int j = 0; j < 16; ++j) {
      s1 += (v[j].x + v[j].y) + (v[j].z + v[j].w);
      s2 = fmaf(v[j].x, v[j].x, fmaf(v[j].y, v[j].y, fmaf(v[j].z, v[j].z, fmaf(v[j].w, v[j].w, s2))));
    }
    float mu = s1 * (1.0f / S);
    float var = fmaxf(s2 * (1.0f / S) - mu * mu, 1e-30f);
    float scale = -2.0f / sqrtf(var);   // bake -2: d2 = sqx+64 + A.(-2z)
#pragma unroll
    for (int s8 = 0; s8 < 8; ++s8) {
      float4 a = v[s8 * 2], b = v[s8 * 2 + 1];
      uint4 pk;
      pk.x = pkbf((a.x - mu) * scale, (a.y - mu) * scale);
      pk.y = pkbf((a.z - mu) * scale, (a.w - mu) * scale);
      pk.z = pkbf((b.x - mu) * scale, (b.y - mu) * scale);
      pk.w = pkbf((b.z - mu) * scale, (b.w - mu) * scale);
      int chunk = (c * 4 + (kl >> 4) * 2 + (s8 >> 2)) * 512 + ((s8 & 3) * 16 + (kl & 15)) * 8;
      *(uint4*)&blds[chunk] = pk;
    }
  }
  __syncthreads();  // xf(0) + blds ready

  // ---- build(0): xcop + sqx for tile 0 ----
  {
    const int c = wave;
#pragma unroll
    for (int j = 0; j < 11; ++j) {
      int d = j * 64 + lane;
      if (d < 4 * 168) {
        int r = d / 168, i2 = d - r * 168;
        int i = i2 * 2;
        *(unsigned int*)&xcop[c][r][i] = pkbf(xf[c * XFS + i + r], xf[c * XFS + i + r + 1]);
      }
    }
  }
  {
    int c = t >> 6, wl = (t & 63) * 4;
    const float* xr = xf + c * XFS + wl;
    float p0 = 0.f, p1 = 0.f, p2 = 0.f, p3 = 0.f;
#pragma unroll
    for (int si = 0; si < S; si += 4) {
      p0 = fmaf(xr[si], xr[si], p0);       p1 = fmaf(xr[si + 1], xr[si + 1], p1);
      p2 = fmaf(xr[si + 2], xr[si + 2], p2); p3 = fmaf(xr[si + 3], xr[si + 3], p3);
    }
    float s0 = 64.0f + (p0 + p1) + (p2 + p3);  // +64 = sum(z^2), exact for pop. z-norm
    sqx[c][wl] = s0;
#pragma unroll
    for (int q = 1; q < 4; ++q) {
      float a = xr[S - 1 + q], b = xr[q - 1];
      s0 += a * a - b * b;
      sqx[c][wl + q] = s0;
    }
  }

  const float INF = __int_as_float(0x7F800000);
  float best = INF;
  const int abase = (col - r4) + quad * 8;  // multiple of 4 -> 8B-aligned b64 reads

  for (int tw = 0; tw < NT; ++tw) {
    __syncthreads();  // build(tw) done: xcop/sqx ready; xf free for next tile

    // issue next tile's global x loads first (land under the MFMA compute)
    if (tw + 1 < NT) {
      const int w0n = (tw + 1) * TW;
#pragma unroll
      for (int j = 0; j < 6; ++j) {
        int s = j * 512 + t;
        if (s < C * XFS) {
          int c = s / XFS, e = s - c * XFS;
          int g = w0n + e;
          xf[s] = (e < 336 && g < L) ? xn[c * L + g] : 0.0f;
        }
      }
    }

    // ---- barrier-free channel loop ----
    f32x4 dsum[4];
#pragma unroll
    for (int a = 0; a < 4; ++a) dsum[a] = f32x4{0.f, 0.f, 0.f, 0.f};

#pragma unroll 1
    for (int c = 0; c < C; ++c) {
      const unsigned short* bb = blds + c * 2048;
      bf16x8 b0 = *(const bf16x8*)(bb + (kgrp * 2 + 0) * 512 + lane * 8);
      bf16x8 b1 = *(const bf16x8*)(bb + (kgrp * 2 + 1) * 512 + lane * 8);
      const unsigned short* xc = &xcop[c][r4][0];

      f32x4 acc[4];
#pragma unroll
      for (int wt = 0; wt < 4; ++wt)   // acc init = sqx + 64 (+sqs) : one ds_read
        acc[wt] = *(const f32x4*)&sqx[c][wgrp * 64 + wt * 16 + quad * 4];
#pragma unroll
      for (int wt = 0; wt < 4; ++wt) {
        int bidx = abase + wgrp * 64 + wt * 16;
        short4v lo = *(const short4v*)(xc + bidx);
        short4v hi = *(const short4v*)(xc + bidx + 4);
        bf16x8 af = __builtin_shufflevector(lo, hi, 0, 1, 2, 3, 4, 5, 6, 7);
        acc[wt] = __builtin_amdgcn_mfma_f32_16x16x32_bf16(af, b0, acc[wt], 0, 0, 0);
      }
#pragma unroll
      for (int wt = 0; wt < 4; ++wt) {
        int bidx = abase + wgrp * 64 + wt * 16 + 32;
        short4v lo = *(const short4v*)(xc + bidx);
        short4v hi = *(const short4v*)(xc + bidx + 4);
        bf16x8 af = __builtin_shufflevector(lo, hi, 0, 1, 2, 3, 4, 5, 6, 7);
        acc[wt] = __builtin_amdgcn_mfma_f32_16x16x32_bf16(af, b1, acc[wt], 0, 0, 0);
      }
#pragma unroll
      for (int wt = 0; wt < 4; ++wt)
#pragma unroll
        for (int i = 0; i < 4; ++i)
          dsum[wt][i] += __builtin_amdgcn_sqrtf(fmaxf(acc[wt][i], 0.0f));
    }

    // per-tile min-reduce into best
    float mv = INF;
#pragma unroll
    for (int wt = 0; wt < 4; ++wt)
#pragma unroll
      for (int i = 0; i < 4; ++i) {
        int w = tw * TW + wgrp * 64 + wt * 16 + quad * 4 + i;
        mv = (w < W) ? fminf(mv, dsum[wt][i]) : mv;
      }
    mv = fminf(mv, __shfl_xor(mv, 16));
    mv = fminf(mv, __shfl_xor(mv, 32));
    best = fminf(best, mv);

    __syncthreads();  // compute(tw) done (xcop free); xf(tw+1) ready
    if (tw + 1 < NT) {
      const int c = wave;
#pragma unroll
      for (int j = 0; j < 11; ++j) {
        int d = j * 64 + lane;
        if (d < 4 * 168) {
          int r = d / 168, i2 = d - r * 168;
          int i = i2 * 2;
          *(unsigned int*)&xcop[c][r][i] = pkbf(xf[c * XFS + i + r], xf[c * XFS + i + r + 1]);
        }
      }
      int cc = t >> 6, wl = (t & 63) * 4;
      const float* xr = xf + cc * XFS + wl;
      float p0 = 0.f, p1 = 0.f, p2 = 0.f, p3 = 0.f;
#pragma unroll
      for (int si = 0; si < S; si += 4) {
        p0 = fmaf(xr[si], xr[si], p0);       p1 = fmaf(xr[si + 1], xr[si + 1], p1);
        p2 = fmaf(xr[si + 2], xr[si + 2], p2); p3 = fmaf(xr[si + 3], xr[si + 3], p3);
      }
      float s0 = 64.0f + (p0 + p1) + (p2 + p3);
      sqx[cc][wl] = s0;
#pragma unroll
      for (int q = 1; q < 4; ++q) {
        float a = xr[S - 1 + q], b = xr[q - 1];
        s0 += a * a - b * b;
        sqx[cc][wl + q] = s0;
      }
    }
  }

  // ---- cross-wave min (4 wgrp waves share each k) via xf scratch; plain store ----
  float* red = xf;  // xf dead now
  if (quad == 0) red[wave * 16 + col] = best;
  __syncthreads();
  if (t < 32) {
    int kg = t >> 4, cl = t & 15;
    float m = red[(0 * 2 + kg) * 16 + cl];
    m = fminf(m, red[(1 * 2 + kg) * 16 + cl]);
    m = fminf(m, red[(2 * 2 + kg) * 16 + cl]);
    m = fminf(m, red[(3 * 2 + kg) * 16 + cl]);
    out[n * K + kblk * 32 + kg * 16 + cl] = m;
  }
}

extern "C" void kernel_launch(void* const* d_in, const int* in_sizes, int n_in,
                              void* d_out, int out_size, void* d_ws, size_t ws_size,
                              hipStream_t stream) {
  const float* x = (const float*)d_in[0];    // (64, 8, 2048) fp32
  const float* sh = (const float*)d_in[1];   // (8, 128, 64) fp32
  float* out = (float*)d_out;                // (64, 1, 128) fp32
  mega_kernel<<<dim3(4, NB), 512, 0, stream>>>(x, sh, out);
}

// Round 13
// 91.452 us; speedup vs baseline: 1.2367x; 1.2367x over previous
//
#include <hip/hip_runtime.h>
#include <hip/hip_bf16.h>
#include <math.h>

#define C 8
#define K 128
#define S 64
#define L 2048
#define NB 64
#define W (L - S + 1)   // 1985
#define TW 128
#define NTW 16
#define NKB 2           // K split across 2 blocks (64 k each)
#define XCS 208         // xcop stride shorts: 104 dw = 8 banks mod 32 -> conflict-free b128
#define XFS 200         // fp32 x scratch stride (192 data + 8 zero pad)

typedef __attribute__((ext_vector_type(8))) short bf16x8;
typedef __attribute__((ext_vector_type(4))) float f32x4;

__device__ __forceinline__ unsigned short f2bf(float f) {
  unsigned int u = __float_as_uint(f);
  u += 0x7FFFu + ((u >> 16) & 1u);   // RNE
  return (unsigned short)(u >> 16);
}

// packed f32x2 -> bf16x2 (v_cvt_pk_bf16_f32 on gfx950)
__device__ __forceinline__ unsigned int pkbf(float a, float b) {
  __hip_bfloat162 h = __float22bfloat162_rn(make_float2(a, b));
  return *reinterpret_cast<unsigned int*>(&h);
}

// full-wave ONLY (R8 lesson: lane-predicated global_load_lds explodes traffic)
__device__ __forceinline__ void gll16(const void* g, void* l) {
  __builtin_amdgcn_global_load_lds((const __attribute__((address_space(1))) void*)g,
                                   (__attribute__((address_space(3))) void*)l, 16, 0, 0);
}

// prep: z-normalize shapelets -> bf16 * (-2), B-fragment order grouped by kblk
// (8 KB contiguous per (kblk, c)); init out to +inf. NOTE: sum(z^2) == S == 64
// exactly (population z-norm), so no per-k sqs is needed anywhere.
__global__ __launch_bounds__(256) void prep_kernel(const float* __restrict__ sh,
                                                   unsigned short* __restrict__ shzB,
                                                   float* __restrict__ out) {
  int tid = blockIdx.x * 256 + threadIdx.x;
  if (tid < NB * K) out[tid] = __int_as_float(0x7F800000);
  int gid = blockIdx.x * 4 + (threadIdx.x >> 6);  // c*K + k
  int lane = threadIdx.x & 63;                    // = s
  float v = sh[(size_t)gid * S + lane];
  float s1 = v, s2 = v * v;
#pragma unroll
  for (int off = 32; off > 0; off >>= 1) {
    s1 += __shfl_down(s1, off);
    s2 += __shfl_down(s2, off);
  }
  s1 = __shfl(s1, 0);
  s2 = __shfl(s2, 0);
  float mu = s1 * (1.0f / S);
  float sd = sqrtf(fmaxf(s2 * (1.0f / S) - mu * mu, 0.0f));
  float z = (v - mu) / sd;
  int c = gid >> 7, k = gid & (K - 1), s = lane;
  // layout: [k>>6][c][((k>>4)&3)*2 + (s>>5)][lane'=((s>>3)&3)*16+(k&15)][s&7]
  int idx = (k >> 6) * 32768 + c * 4096 + ((((k >> 4) & 3) * 2) + (s >> 5)) * 512 +
            ((((s >> 3) & 3) * 16 + (k & 15)) * 8) + (s & 7);
  shzB[idx] = f2bf(-2.0f * z);   // bake the -2 of d2 = (sqx + 64) - 2*cross
}

// main: block = 128w x 64k (kblk), 512 threads = 8 waves, wave tile 64w x 16k.
// LDS 38 KB -> 4 blocks/CU. Channel loop:
//   [READY] -> B ds_reads -> [DONE] -> prefetch B[c+1] -> acc(ds_read)+MFMA+epilogue
// acc init is a BARE ds_read of sqx (the +64 = sum(z^2) is pre-biased in) —
// no per-channel adds, no sqs array (R13 change vs R10).
__global__ __launch_bounds__(512, 4) void main_kernel(const float* __restrict__ x,
                                                      const unsigned short* __restrict__ shzB,
                                                      int* __restrict__ out) {
  __shared__ __align__(16) unsigned short bbuf[4096];      // 8 KB: B[c] for this kblk
  __shared__ __align__(16) unsigned short xcop[C][8][XCS]; // 26 KB: 8 shifted copies
  __shared__ __align__(16) float sqx[C][TW];               // 4 KB (pre-biased +64)

  const int t = threadIdx.x;
  const int lane = t & 63;
  const int wave = t >> 6;     // 0..7
  const int wgrp = wave & 1;   // w-offset 64
  const int kgrp = wave >> 1;  // 0..3 : k-offset 16*kgrp
  const int col = lane & 15;
  const int quad = lane >> 4;
  const int n = blockIdx.z;
  const int kblk = blockIdx.y;
  const int w0 = blockIdx.x * TW;
  const float* xn = x + (size_t)n * C * L;
  const unsigned short* bsrc = shzB + kblk * 32768;

  // ---- stage fp32 x segment into bbuf-as-scratch (wave c, float4/lane) ----
  float* xf = (float*)bbuf;  // 8 ch x XFS floats = 6.4 KB <= 8 KB
  {
    const int c = wave;
    const int e = lane * 4;
    float4 v; v.x = v.y = v.z = v.w = 0.0f;
    if (lane < 48) {
      int g = w0 + e;
      if (g + 3 < L) {
        v = *(const float4*)(xn + c * L + g);
      } else {  // last w-tile tail; feeds masked windows only
        v.x = (g + 0 < L) ? xn[c * L + g + 0] : 0.0f;
        v.y = (g + 1 < L) ? xn[c * L + g + 1] : 0.0f;
        v.z = (g + 2 < L) ? xn[c * L + g + 2] : 0.0f;
        v.w = (g + 3 < L) ? xn[c * L + g + 3] : 0.0f;
      }
    }
    if (lane < 50) *(float4*)&xf[c * XFS + e] = v;   // lanes 48,49 zero-pad tail
  }
  __syncthreads();

  // ---- build 8 shifted bf16 copies (wave c; r=lane>>3; 12 dwords/lane) ----
  {
    const int cb = wave;
    const int rb = lane >> 3;         // 0..7
    const int c8 = lane & 7;
    const float* xr = xf + cb * XFS;
#pragma unroll
    for (int j = 0; j < 12; ++j) {
      int i = (c8 + j * 8) * 2;       // 0..190 even
      *(unsigned int*)&xcop[cb][rb][i] = pkbf(xr[i + rb], xr[i + rb + 1]);
    }
  }
  // ---- sliding-window fp32 sqx (+64 bias = sum(z^2)): wave c, 2 w/lane ----
  {
    const int c = wave, wl = lane * 2;
    const float* xr = xf + c * XFS;
    float p0 = 0.f, p1 = 0.f, p2 = 0.f, p3 = 0.f;
#pragma unroll
    for (int si = 0; si < S; si += 4) {
      float v0 = xr[wl + si], v1 = xr[wl + si + 1], v2 = xr[wl + si + 2], v3 = xr[wl + si + 3];
      p0 = fmaf(v0, v0, p0); p1 = fmaf(v1, v1, p1);
      p2 = fmaf(v2, v2, p2); p3 = fmaf(v3, v3, p3);
    }
    float s0 = 64.0f + (p0 + p1) + (p2 + p3);
    sqx[c][wl] = s0;
    float a = xr[wl + S], b = xr[wl];
    sqx[c][wl + 1] = s0 + a * a - b * b;
  }
  __syncthreads();  // xf dead -> bbuf free for B

  // ---- B channel 0: one full-wave gll16 per thread (8 KB total) ----
  gll16(bsrc + t * 8, &bbuf[wave * 512]);

  const f32x4 z4 = {0.0f, 0.0f, 0.0f, 0.0f};
  f32x4 dsum[4];
#pragma unroll
  for (int a = 0; a < 4; ++a) dsum[a] = z4;

  const int r8 = col & 7;
  const int abase = wgrp * 64 + (col - r8) + quad * 8;  // multiple of 8 -> b128 aligned

  for (int c = 0; c < C; ++c) {
    __syncthreads();  // READY: bbuf holds B[c] (compiler drains vmcnt here)
    bf16x8 b0 = *(const bf16x8*)(&bbuf[(kgrp * 2 + 0) * 512 + lane * 8]);
    bf16x8 b1 = *(const bf16x8*)(&bbuf[(kgrp * 2 + 1) * 512 + lane * 8]);
    __syncthreads();  // DONE: all waves captured their B fragments

    if (c + 1 < C)    // prefetch lands during the compute below
      gll16(bsrc + (c + 1) * 4096 + t * 8, &bbuf[wave * 512]);

    // ---- barrier-free compute region: acc = ds_read(sqx) -> MFMA -> epilogue ----
    f32x4 acc[4];
#pragma unroll
    for (int wt = 0; wt < 4; ++wt)
      acc[wt] = *(const f32x4*)&sqx[c][wgrp * 64 + wt * 16 + quad * 4];
    const unsigned short* xc = &xcop[c][r8][0];
#pragma unroll
    for (int wt = 0; wt < 4; ++wt) {
      bf16x8 a0 = *(const bf16x8*)(xc + abase + wt * 16);
      acc[wt] = __builtin_amdgcn_mfma_f32_16x16x32_bf16(a0, b0, acc[wt], 0, 0, 0);
    }
#pragma unroll
    for (int wt = 0; wt < 4; ++wt) {
      bf16x8 a1 = *(const bf16x8*)(xc + abase + wt * 16 + 32);
      acc[wt] = __builtin_amdgcn_mfma_f32_16x16x32_bf16(a1, b1, acc[wt], 0, 0, 0);
    }
#pragma unroll
    for (int wt = 0; wt < 4; ++wt)
#pragma unroll
      for (int i = 0; i < 4; ++i)
        dsum[wt][i] += __builtin_amdgcn_sqrtf(fmaxf(acc[wt][i], 0.0f));
  }

  // min over w (regs -> quad shuffles), one atomicMin per k
  const float INF = __int_as_float(0x7F800000);
  int wbase = w0 + wgrp * 64;
  float mv = INF;
#pragma unroll
  for (int wt = 0; wt < 4; ++wt)
#pragma unroll
    for (int i = 0; i < 4; ++i) {
      int w = wbase + wt * 16 + quad * 4 + i;
      mv = (w < W) ? fminf(mv, dsum[wt][i]) : mv;
    }
  mv = fminf(mv, __shfl_xor(mv, 16));
  mv = fminf(mv, __shfl_xor(mv, 32));
  if (quad == 0)
    atomicMin(&out[n * K + kblk * 64 + kgrp * 16 + col], __float_as_int(mv));
}

extern "C" void kernel_launch(void* const* d_in, const int* in_sizes, int n_in,
                              void* d_out, int out_size, void* d_ws, size_t ws_size,
                              hipStream_t stream) {
  const float* x = (const float*)d_in[0];    // (64, 8, 2048) fp32
  const float* sh = (const float*)d_in[1];   // (8, 128, 64) fp32
  float* out = (float*)d_out;                // (64, 1, 128) fp32
  unsigned short* shzB = (unsigned short*)d_ws;  // 128 KB bf16 B-frag layout (scaled -2)

  prep_kernel<<<256, 256, 0, stream>>>(sh, shzB, out);
  main_kernel<<<dim3(NTW, NKB, NB), 512, 0, stream>>>(x, shzB, (int*)out);
}